// Round 5
// baseline (64.732 us; speedup 1.0000x reference)
//
#include <hip/hip_runtime.h>

#define DIM 4096
#define LN_EPS 1e-5f
#define NT 512
#define RPB 8                 // rows per block
#define NWAVES (NT / 64)

typedef float vfloat4 __attribute__((ext_vector_type(4)));

__global__ __launch_bounds__(NT) void crosslayer_ln_kernel(
    const float* __restrict__ x,
    const float* __restrict__ x0,
    const float* __restrict__ w,
    const float* __restrict__ bias,
    const float* __restrict__ gamma,
    const float* __restrict__ beta,
    float* __restrict__ out)
{
    const int tid  = threadIdx.x;
    const int wave = tid >> 6;
    const int lane = tid & 63;
    const int i0 = tid;           // float4 index, 1024 float4 per row
    const int i1 = NT + tid;

    // ---- per-block staging: gamma/beta -> LDS, w/bias -> registers ----
    __shared__ float4 sg[DIM / 4];
    __shared__ float4 sbt[DIM / 4];
    __shared__ float dred[2][NWAVES];
    __shared__ float2 mred[2][NWAVES];

    const float4* __restrict__ wv  = reinterpret_cast<const float4*>(w);
    const float4* __restrict__ bv  = reinterpret_cast<const float4*>(bias);
    const float4* __restrict__ gv  = reinterpret_cast<const float4*>(gamma);
    const float4* __restrict__ btv = reinterpret_cast<const float4*>(beta);

    sg[i0]  = gv[i0];
    sg[i1]  = gv[i1];
    sbt[i0] = btv[i0];
    sbt[i1] = btv[i1];
    const float4 w0 = wv[i0];
    const float4 w1 = wv[i1];
    const float4 b0 = bv[i0];
    const float4 b1 = bv[i1];
    __syncthreads();

    const size_t rowbase = (size_t)blockIdx.x * RPB;

    for (int r = 0; r < RPB; ++r) {
        const size_t row = rowbase + r;
        const float4* __restrict__ x0v = reinterpret_cast<const float4*>(x0 + row * DIM);
        const float4* __restrict__ xv  = reinterpret_cast<const float4*>(x  + row * DIM);
        vfloat4* __restrict__ ov = reinterpret_cast<vfloat4*>(out + row * DIM);

        const float4 a0 = x0v[i0];
        const float4 a1 = x0v[i1];
        const float4 xA = xv[i0];
        const float4 xB = xv[i1];

        // ---- dot(x0, w) ----
        float dot = a0.x*w0.x + a0.y*w0.y + a0.z*w0.z + a0.w*w0.w
                  + a1.x*w1.x + a1.y*w1.y + a1.z*w1.z + a1.w*w1.w;
        #pragma unroll
        for (int o = 1; o < 64; o <<= 1) dot += __shfl_xor(dot, o, 64);
        if (lane == 0) dred[r & 1][wave] = dot;
        __syncthreads();
        float td = 0.f;
        #pragma unroll
        for (int i = 0; i < NWAVES; ++i) td += dred[r & 1][i];
        const float m = 1.f + td;          // pre = m*x + bias

        // ---- pre + moments ----
        float pA0 = fmaf(m, xA.x, b0.x), pA1 = fmaf(m, xA.y, b0.y);
        float pA2 = fmaf(m, xA.z, b0.z), pA3 = fmaf(m, xA.w, b0.w);
        float pB0 = fmaf(m, xB.x, b1.x), pB1 = fmaf(m, xB.y, b1.y);
        float pB2 = fmaf(m, xB.z, b1.z), pB3 = fmaf(m, xB.w, b1.w);

        float sum   = pA0 + pA1 + pA2 + pA3 + pB0 + pB1 + pB2 + pB3;
        float sumsq = pA0*pA0 + pA1*pA1 + pA2*pA2 + pA3*pA3
                    + pB0*pB0 + pB1*pB1 + pB2*pB2 + pB3*pB3;
        #pragma unroll
        for (int o = 1; o < 64; o <<= 1) {
            sum   += __shfl_xor(sum,   o, 64);
            sumsq += __shfl_xor(sumsq, o, 64);
        }
        if (lane == 0) mred[r & 1][wave] = make_float2(sum, sumsq);
        __syncthreads();
        float tsum = 0.f, tsq = 0.f;
        #pragma unroll
        for (int i = 0; i < NWAVES; ++i) {
            const float2 v = mred[r & 1][i];
            tsum += v.x; tsq += v.y;
        }
        const float mean = tsum * (1.f / DIM);
        const float var  = tsq * (1.f / DIM) - mean * mean;
        const float inv  = rsqrtf(var + LN_EPS);

        // ---- normalize + affine (gamma/beta from LDS), nt store ----
        const float4 gA  = sg[i0];
        const float4 gB  = sg[i1];
        const float4 btA = sbt[i0];
        const float4 btB = sbt[i1];
        vfloat4 o0, o1;
        o0.x = fmaf((pA0 - mean) * inv, gA.x, btA.x);
        o0.y = fmaf((pA1 - mean) * inv, gA.y, btA.y);
        o0.z = fmaf((pA2 - mean) * inv, gA.z, btA.z);
        o0.w = fmaf((pA3 - mean) * inv, gA.w, btA.w);
        o1.x = fmaf((pB0 - mean) * inv, gB.x, btB.x);
        o1.y = fmaf((pB1 - mean) * inv, gB.y, btB.y);
        o1.z = fmaf((pB2 - mean) * inv, gB.z, btB.z);
        o1.w = fmaf((pB3 - mean) * inv, gB.w, btB.w);
        __builtin_nontemporal_store(o0, &ov[i0]);
        __builtin_nontemporal_store(o1, &ov[i1]);
    }
}

extern "C" void kernel_launch(void* const* d_in, const int* in_sizes, int n_in,
                              void* d_out, int out_size, void* d_ws, size_t ws_size,
                              hipStream_t stream) {
    const float* x     = (const float*)d_in[0];
    const float* x0    = (const float*)d_in[1];
    const float* w     = (const float*)d_in[2];
    const float* bias  = (const float*)d_in[3];
    const float* gamma = (const float*)d_in[4];
    const float* beta  = (const float*)d_in[5];
    float* out = (float*)d_out;

    const int B = in_sizes[0] / DIM;       // 8192
    const int nblocks = B / RPB;           // 1024
    crosslayer_ln_kernel<<<nblocks, NT, 0, stream>>>(x, x0, w, bias, gamma, beta, out);
}